// Round 11
// baseline (74.997 us; speedup 1.0000x reference)
//
#include <hip/hip_runtime.h>
#include <hip/hip_bf16.h>

using u16 = unsigned short;
using u32 = unsigned int;
typedef float f32x4 __attribute__((ext_vector_type(4)));
typedef float f32x2 __attribute__((ext_vector_type(2)));
typedef __bf16 bf16x8 __attribute__((ext_vector_type(8)));

// ---- helpers ----------------------------------------------------------------
static __device__ __forceinline__ float bflo(u32 u) { return __uint_as_float(u << 16); }
static __device__ __forceinline__ float bfhi(u32 u) { return __uint_as_float(u & 0xffff0000u); }

static __device__ __forceinline__ u32 pack2(float a, float b) {
  __hip_bfloat16 ha = __float2bfloat16(a);
  __hip_bfloat16 hb = __float2bfloat16(b);
  u16 ra, rb;
  __builtin_memcpy(&ra, &ha, 2);
  __builtin_memcpy(&rb, &hb, 2);
  return (u32)ra | ((u32)rb << 16);
}

static __device__ __forceinline__ u16 f2bf(float f) {
  u32 u = __float_as_uint(f);
  u32 r = (u + 0x7fffu + ((u >> 16) & 1u)) >> 16;
  return (u16)r;
}

static __device__ __forceinline__ bf16x8 as_bf(uint4 v) {
  bf16x8 r;
  __builtin_memcpy(&r, &v, 16);
  return r;
}

// truncating pack of two blended f32 -> bf16x2, single v_perm_b32
static __device__ __forceinline__ u32 packtrunc(float lo, float hi) {
  return __builtin_amdgcn_perm(__float_as_uint(hi), __float_as_uint(lo), 0x07060302u);
}

static __device__ __forceinline__ f32x2 unpk(u32 u) {
  f32x2 r;
  r.x = bflo(u);
  r.y = bfhi(u);
  return r;
}

// 4-corner bilinear blend of 8 bf16 channels -> bf16x8 fragment (as uint4)
static __device__ __forceinline__ uint4 blend4(uint4 a, uint4 b, uint4 c, uint4 d,
                                               float w00, float w01, float w10, float w11) {
  uint4 r;
#pragma unroll
  for (int j = 0; j < 4; j++) {
    f32x2 v = unpk((&a.x)[j]) * w00;
    v += unpk((&b.x)[j]) * w01;
    v += unpk((&c.x)[j]) * w10;
    v += unpk((&d.x)[j]) * w11;
    (&r.x)[j] = packtrunc(v.x, v.y);
  }
  return r;
}

// ---- kernel 1: x [B,C,H,W] f32 -> xT [B,H,W,C] bf16 (float4 loads) ----------
__global__ __launch_bounds__(256) void transpose_k(const float* __restrict__ x,
                                                   u16* __restrict__ xT) {
  const int bid = blockIdx.x;
  const int b = bid >> 6, y = bid & 63;
  const int t = threadIdx.x;
  const int cg = t >> 4;            // channel-group: channels cg*8..cg*8+7
  const int w4 = (t & 15) * 4;      // 4 consecutive w per thread
  const float* xp = x + ((size_t)(b * 128) * 64 + y) * 64;
  u16* op = xT + ((size_t)(b * 64 + y) * 64) * 128;
  float4 v[8];
#pragma unroll
  for (int k = 0; k < 8; k++)
    v[k] = *(const float4*)(xp + (cg * 8 + k) * 4096 + w4);
#pragma unroll
  for (int ww = 0; ww < 4; ww++) {
    u32 rr[4];
#pragma unroll
    for (int p = 0; p < 4; p++)
      rr[p] = pack2(((const float*)&v[2 * p])[ww], ((const float*)&v[2 * p + 1])[ww]);
    uint4 r;
    r.x = rr[0]; r.y = rr[1]; r.z = rr[2]; r.w = rr[3];
    *(uint4*)(op + (w4 + ww) * 128 + cg * 8) = r;
  }
}

// ---- kernel 2: weff via LDS-staged w-slice ----------------------------------
// grid 144 = ks(72) x nh(2). Stage wslice[oc][kc] (84x32 f32, 10.5KB) once;
// inner loop reads wf (L2-hot, lane-broadcast) + conflict-free LDS.
// Output element idx = ((ks*6+nt)*64 + lg*16 + lrow)*8 + j, n=nt*16+lrow,
// kc=lg*8+j (same fragment layout as before).
__global__ __launch_bounds__(256) void weff_k(const float* __restrict__ w0,
                                              const float* __restrict__ w1,
                                              const float* __restrict__ wf,
                                              u16* __restrict__ weffg) {
  __shared__ float ws[84][32];
  const int blk = blockIdx.x;
  const int ks = blk >> 1, nh = blk & 1;
  const int br = ks >= 36 ? 1 : 0;
  const int ksb = ks - br * 36;
  const int tap = ksb >> 2, chunk = ksb & 3;
  const float* w = br ? w1 : w0;
  const int t = threadIdx.x;
  for (int i = t; i < 2688; i += 256) {
    int oc = i >> 5, kc = i & 31;
    ws[oc][kc] = w[oc * 1152 + (chunk * 32 + kc) * 9 + tap];
  }
  __syncthreads();
  const int kc = t & 31, ng = t >> 5;   // ng 0..7
  const int n0 = nh * 48 + ng * 6;
  float accv[6] = {0.f, 0.f, 0.f, 0.f, 0.f, 0.f};
#pragma unroll 4
  for (int oc = 0; oc < 84; oc++) {
    float wv_ = ws[oc][kc];
#pragma unroll
    for (int i = 0; i < 6; i++) {
      int n = n0 + i;
      float f = (n < 84) ? wf[n * 168 + br * 84 + oc] : 0.f;
      accv[i] += f * wv_;
    }
  }
#pragma unroll
  for (int i = 0; i < 6; i++) {
    int n = n0 + i;
    int nt = n >> 4, lrow = n & 15, lg = kc >> 3, j = kc & 7;
    int idx = ((ks * 6 + nt) * 64 + lg * 16 + lrow) * 8 + j;
    weffg[idx] = f2bf(n < 84 ? accv[i] : 0.f);
  }
}

// ---- kernel 3: LDS-resident row-window deform-sample + GEMM, 16 waves -------
// 512 blocks = (b:8 -> XCD) x (h:64), 1024 threads (16 waves = 4/SIMD).
// Wave wv: pxh = wv>>2 (16-px quarter), sub = wv&3 -> br = sub>>1, cp = sub&1.
// Wave: 16 px x 96 out x K=576 (9 taps x 2 chunks of 32 ch).
// r11 vs r10: same LDS window (the r10 win), but 2x waves/SIMD with halved
// per-wave tile (acc 24 + q 32 + weff 24 ~ 110 regs <= 128 -> 4 waves/SIMD).
// Same total MFMA/blend/LDS work; 2x VALU issue slots to hide dependency gaps.
__global__ __launch_bounds__(1024, 1) void deform_main(
    const u16* __restrict__ xT, const u16* __restrict__ weffg,
    const float* __restrict__ dm0, const float* __restrict__ dm1,
    const float* __restrict__ bias, float* __restrict__ out) {
  __shared__ uint4 ldsbuf[9360];   // 9 rows * 16 slots * 65 * 16B = 146.25 KiB

  const int t = threadIdx.x;
  const int wv = t >> 6, lane = t & 63;
  const int pxh = wv >> 2;             // 0..3
  const int sub = wv & 3;              // br*2 + cp
  const int br = sub >> 1, cp = sub & 1;
  const int lrow = lane & 15, lg = lane >> 4;
  const int blk = blockIdx.x;
  const int b = blk & 7, h = blk >> 3;
  const int px0 = pxh * 16;

  const u16* xb = xT + (size_t)b * 524288;

  // ---- stage rows [h-4, h+4] into LDS (coalesced 16B, 9 iters/thread) ----
#pragma unroll
  for (int k = 0; k < 9; k++) {
    int u = t + (k << 10);         // < 9216
    int i = u >> 10;               // window row 0..8
    int ul = u & 1023;             // x*16 + slot
    int ysr = min(63, max(0, h - 4 + i));
    uint4 v = *(const uint4*)(xb + ysr * 8192 + ul * 8);
    int s = ul & 15, xx = ul >> 4;
    ldsbuf[(i * 16 + s) * 65 + xx] = v;
  }
  __syncthreads();

  const float* dmb = (br ? dm1 : dm0) + (size_t)b * 73728 + h * 64 + px0 + lrow;
  const u16* wbase = weffg + (size_t)(br * 36 + cp * 2) * 3072 + lane * 8;

  f32x4 acc[6];
#pragma unroll
  for (int i = 0; i < 6; i++) acc[i] = f32x4{0.f, 0.f, 0.f, 0.f};

  float w00, w01, w10, w11;
  int x0A, x1A, yw0A, yw1A;            // yw*: window-relative rows (may be OOW)
  float dyN, dxN;
  uint4 q[8];                          // 2 chunks x 4 corners in flight

  auto tapstate = [&](int ty, int tx, float dy, float dx) {
    float pyf = (float)(h + ty - 1) + dy;
    float pxf = (float)(px0 + lrow + tx - 1) + dx;
    float y0f = floorf(pyf), x0f = floorf(pxf);
    int y0 = (int)y0f, x0 = (int)x0f;
    float wy1 = pyf - y0f, wx1 = pxf - x0f;
    float wy0 = 1.f - wy1, wx0 = 1.f - wx1;
    int y1 = y0 + 1, x1 = x0 + 1;
    wy0 *= ((u32)y0 < 64u) ? 1.f : 0.f;
    wy1 *= ((u32)y1 < 64u) ? 1.f : 0.f;
    wx0 *= ((u32)x0 < 64u) ? 1.f : 0.f;
    wx1 *= ((u32)x1 < 64u) ? 1.f : 0.f;
    w00 = wy0 * wx0; w01 = wy0 * wx1;
    w10 = wy1 * wx0; w11 = wy1 * wx1;
    int y0c = min(63, max(0, y0)), y1c = min(63, max(0, y1));
    x0A = min(63, max(0, x0));
    x1A = min(63, max(0, x1));
    yw0A = y0c - h + 4;                // in-window iff 0..8
    yw1A = y1c - h + 4;
  };

  auto issue_lds = [&]() {
    int y0w = min(8, max(0, yw0A));
    int y1w = min(8, max(0, yw1A));
#pragma unroll
    for (int c = 0; c < 2; c++) {
      int slot = cp * 8 + c * 4 + lg;
      int b0 = (y0w * 16 + slot) * 65;
      int b1 = (y1w * 16 + slot) * 65;
      q[c * 4 + 0] = ldsbuf[b0 + x0A];
      q[c * 4 + 1] = ldsbuf[b0 + x1A];
      q[c * 4 + 2] = ldsbuf[b1 + x0A];
      q[c * 4 + 3] = ldsbuf[b1 + x1A];
    }
  };

  // rare out-of-window fallback: predicated global corner loads
  auto oow_fix = [&]() {
    bool bad = ((u32)yw0A > 8u) | ((u32)yw1A > 8u);
    if (__any(bad)) {
      if ((u32)yw0A > 8u) {
        const u16* p = xb + (yw0A + h - 4) * 8192 + cp * 64 + lg * 8;
#pragma unroll
        for (int c = 0; c < 2; c++) {
          q[c * 4 + 0] = *(const uint4*)(p + c * 32 + x0A * 128);
          q[c * 4 + 1] = *(const uint4*)(p + c * 32 + x1A * 128);
        }
      }
      if ((u32)yw1A > 8u) {
        const u16* p = xb + (yw1A + h - 4) * 8192 + cp * 64 + lg * 8;
#pragma unroll
        for (int c = 0; c < 2; c++) {
          q[c * 4 + 2] = *(const uint4*)(p + c * 32 + x0A * 128);
          q[c * 4 + 3] = *(const uint4*)(p + c * 32 + x1A * 128);
        }
      }
    }
  };

  // ---- prologue: tap 0 state + reads, dm(tap1) ----
  {
    float dy0 = dmb[0], dx0 = dmb[4096];
    tapstate(0, 0, dy0, dx0);
  }
  issue_lds();
  oow_fix();
  dyN = dmb[2 * 4096];
  dxN = dmb[3 * 4096];

#pragma unroll 1
  for (int tap = 0; tap < 9; tap++) {
    const u16* wp = wbase + (size_t)(tap * 4) * 3072;

    // ---- chunk c=0 ----
    {
      uint4 wq0 = *(const uint4*)(wp);
      uint4 wq1 = *(const uint4*)(wp + 512);
      uint4 wq2 = *(const uint4*)(wp + 1024);
      uint4 wq3 = *(const uint4*)(wp + 1536);
      uint4 wq4 = *(const uint4*)(wp + 2048);
      uint4 wq5 = *(const uint4*)(wp + 2560);
      uint4 a0 = blend4(q[0], q[1], q[2], q[3], w00, w01, w10, w11);
      bf16x8 af0 = as_bf(a0);
      __builtin_amdgcn_s_setprio(1);
      acc[0] = __builtin_amdgcn_mfma_f32_16x16x32_bf16(as_bf(wq0), af0, acc[0], 0, 0, 0);
      acc[1] = __builtin_amdgcn_mfma_f32_16x16x32_bf16(as_bf(wq1), af0, acc[1], 0, 0, 0);
      acc[2] = __builtin_amdgcn_mfma_f32_16x16x32_bf16(as_bf(wq2), af0, acc[2], 0, 0, 0);
      acc[3] = __builtin_amdgcn_mfma_f32_16x16x32_bf16(as_bf(wq3), af0, acc[3], 0, 0, 0);
      acc[4] = __builtin_amdgcn_mfma_f32_16x16x32_bf16(as_bf(wq4), af0, acc[4], 0, 0, 0);
      acc[5] = __builtin_amdgcn_mfma_f32_16x16x32_bf16(as_bf(wq5), af0, acc[5], 0, 0, 0);
      __builtin_amdgcn_s_setprio(0);
    }

    // ---- chunk c=1 ----
    {
      uint4 wq0 = *(const uint4*)(wp + 3072);
      uint4 wq1 = *(const uint4*)(wp + 3584);
      uint4 wq2 = *(const uint4*)(wp + 4096);
      uint4 wq3 = *(const uint4*)(wp + 4608);
      uint4 wq4 = *(const uint4*)(wp + 5120);
      uint4 wq5 = *(const uint4*)(wp + 5632);
      uint4 a1 = blend4(q[4], q[5], q[6], q[7], w00, w01, w10, w11);

      // next tap: state + ds-issue (q now dead), dm prefetch a tap ahead
      if (tap < 8) {
        int tn = tap + 1;
        int ty = (tn * 11) >> 5;     // tn/3
        int tx = tn - ty * 3;
        tapstate(ty, tx, dyN, dxN);
        issue_lds();
        oow_fix();
        if (tap < 7) {
          dyN = dmb[(2 * tn + 2) * 4096];
          dxN = dmb[(2 * tn + 3) * 4096];
        }
      }

      bf16x8 af1 = as_bf(a1);
      __builtin_amdgcn_s_setprio(1);
      acc[0] = __builtin_amdgcn_mfma_f32_16x16x32_bf16(as_bf(wq0), af1, acc[0], 0, 0, 0);
      acc[1] = __builtin_amdgcn_mfma_f32_16x16x32_bf16(as_bf(wq1), af1, acc[1], 0, 0, 0);
      acc[2] = __builtin_amdgcn_mfma_f32_16x16x32_bf16(as_bf(wq2), af1, acc[2], 0, 0, 0);
      acc[3] = __builtin_amdgcn_mfma_f32_16x16x32_bf16(as_bf(wq3), af1, acc[3], 0, 0, 0);
      acc[4] = __builtin_amdgcn_mfma_f32_16x16x32_bf16(as_bf(wq4), af1, acc[4], 0, 0, 0);
      acc[5] = __builtin_amdgcn_mfma_f32_16x16x32_bf16(as_bf(wq5), af1, acc[5], 0, 0, 0);
      __builtin_amdgcn_s_setprio(0);
    }
  }

  // ---- reduce the 4 K-partials per pxh group (reuse staging LDS), store ----
  __syncthreads();                       // all LDS gather reads done
  const int rbase = pxh * 1152;          // uint4 units; 4*1152 = 4608 <= 9360
  if (sub > 0) {
#pragma unroll
    for (int nt = 0; nt < 6; nt++) {
      uint4 v;
      __builtin_memcpy(&v, &acc[nt], 16);
      ldsbuf[rbase + ((sub - 1) * 6 + nt) * 64 + lane] = v;
    }
  }
  __syncthreads();
  if (sub == 0) {
#pragma unroll
    for (int nt = 0; nt < 6; nt++) {
#pragma unroll
      for (int r = 0; r < 3; r++) {
        uint4 v = ldsbuf[rbase + (r * 6 + nt) * 64 + lane];
        f32x4 fv;
        __builtin_memcpy(&fv, &v, 16);
#pragma unroll
        for (int j = 0; j < 4; j++) acc[nt][j] += fv[j];
      }
    }
    float* op = out + ((size_t)b * 84 * 64 + h) * 64 + px0;
#pragma unroll
    for (int nt = 0; nt < 6; nt++) {
#pragma unroll
      for (int j = 0; j < 4; j++) {
        int o = nt * 16 + lg * 4 + j;
        if (o < 84) op[(size_t)o * 4096 + lrow] = acc[nt][j] + bias[o];
      }
    }
  }
}

// ---- launch -----------------------------------------------------------------
extern "C" void kernel_launch(void* const* d_in, const int* in_sizes, int n_in,
                              void* d_out, int out_size, void* d_ws, size_t ws_size,
                              hipStream_t stream) {
  const float* x   = (const float*)d_in[0];
  const float* dm0 = (const float*)d_in[1];
  const float* dm1 = (const float*)d_in[2];
  const float* w0  = (const float*)d_in[3];
  const float* w1  = (const float*)d_in[4];
  const float* wf  = (const float*)d_in[5];
  const float* bf  = (const float*)d_in[6];
  float* out = (float*)d_out;

  u16* xT = (u16*)d_ws;                                               // 8 MiB
  u16* weffg = (u16*)((char*)d_ws + (size_t)8 * 64 * 64 * 128 * 2);   // 432 KiB

  transpose_k<<<512, 256, 0, stream>>>(x, xT);
  weff_k<<<144, 256, 0, stream>>>(w0, w1, wf, weffg);
  deform_main<<<512, 1024, 0, stream>>>(xT, weffg, dm0, dm1, bf, out);
}

// Round 12
// 74.644 us; speedup vs baseline: 1.0047x; 1.0047x over previous
//
#include <hip/hip_runtime.h>
#include <hip/hip_bf16.h>

using u16 = unsigned short;
using u32 = unsigned int;
typedef float f32x4 __attribute__((ext_vector_type(4)));
typedef float f32x2 __attribute__((ext_vector_type(2)));
typedef __bf16 bf16x8 __attribute__((ext_vector_type(8)));

// ---- helpers ----------------------------------------------------------------
static __device__ __forceinline__ float bflo(u32 u) { return __uint_as_float(u << 16); }
static __device__ __forceinline__ float bfhi(u32 u) { return __uint_as_float(u & 0xffff0000u); }

static __device__ __forceinline__ u32 pack2(float a, float b) {
  __hip_bfloat16 ha = __float2bfloat16(a);
  __hip_bfloat16 hb = __float2bfloat16(b);
  u16 ra, rb;
  __builtin_memcpy(&ra, &ha, 2);
  __builtin_memcpy(&rb, &hb, 2);
  return (u32)ra | ((u32)rb << 16);
}

static __device__ __forceinline__ u16 f2bf(float f) {
  u32 u = __float_as_uint(f);
  u32 r = (u + 0x7fffu + ((u >> 16) & 1u)) >> 16;
  return (u16)r;
}

static __device__ __forceinline__ bf16x8 as_bf(uint4 v) {
  bf16x8 r;
  __builtin_memcpy(&r, &v, 16);
  return r;
}

// truncating pack of two blended f32 -> bf16x2, single v_perm_b32
static __device__ __forceinline__ u32 packtrunc(float lo, float hi) {
  return __builtin_amdgcn_perm(__float_as_uint(hi), __float_as_uint(lo), 0x07060302u);
}

static __device__ __forceinline__ f32x2 unpk(u32 u) {
  f32x2 r;
  r.x = bflo(u);
  r.y = bfhi(u);
  return r;
}

// 4-corner bilinear blend of 8 bf16 channels -> bf16x8 fragment (as uint4)
static __device__ __forceinline__ uint4 blend4(uint4 a, uint4 b, uint4 c, uint4 d,
                                               float w00, float w01, float w10, float w11) {
  uint4 r;
#pragma unroll
  for (int j = 0; j < 4; j++) {
    f32x2 v = unpk((&a.x)[j]) * w00;
    v += unpk((&b.x)[j]) * w01;
    v += unpk((&c.x)[j]) * w10;
    v += unpk((&d.x)[j]) * w11;
    (&r.x)[j] = packtrunc(v.x, v.y);
  }
  return r;
}

// ---- kernel 1: x [B,C,H,W] f32 -> xT [B,H,W,C] bf16 (float4 loads) ----------
__global__ __launch_bounds__(256) void transpose_k(const float* __restrict__ x,
                                                   u16* __restrict__ xT) {
  const int bid = blockIdx.x;
  const int b = bid >> 6, y = bid & 63;
  const int t = threadIdx.x;
  const int cg = t >> 4;            // channel-group: channels cg*8..cg*8+7
  const int w4 = (t & 15) * 4;      // 4 consecutive w per thread
  const float* xp = x + ((size_t)(b * 128) * 64 + y) * 64;
  u16* op = xT + ((size_t)(b * 64 + y) * 64) * 128;
  float4 v[8];
#pragma unroll
  for (int k = 0; k < 8; k++)
    v[k] = *(const float4*)(xp + (cg * 8 + k) * 4096 + w4);
#pragma unroll
  for (int ww = 0; ww < 4; ww++) {
    u32 rr[4];
#pragma unroll
    for (int p = 0; p < 4; p++)
      rr[p] = pack2(((const float*)&v[2 * p])[ww], ((const float*)&v[2 * p + 1])[ww]);
    uint4 r;
    r.x = rr[0]; r.y = rr[1]; r.z = rr[2]; r.w = rr[3];
    *(uint4*)(op + (w4 + ww) * 128 + cg * 8) = r;
  }
}

// ---- kernel 2: weff via LDS-staged w-slice ----------------------------------
// grid 144 = ks(72) x nh(2). Stage wslice[oc][kc] (84x32 f32, 10.5KB) once;
// inner loop reads wf (L2-hot, lane-broadcast) + conflict-free LDS.
// Output element idx = ((ks*6+nt)*64 + lg*16 + lrow)*8 + j, n=nt*16+lrow,
// kc=lg*8+j (same fragment layout as before).
__global__ __launch_bounds__(256) void weff_k(const float* __restrict__ w0,
                                              const float* __restrict__ w1,
                                              const float* __restrict__ wf,
                                              u16* __restrict__ weffg) {
  __shared__ float ws[84][32];
  const int blk = blockIdx.x;
  const int ks = blk >> 1, nh = blk & 1;
  const int br = ks >= 36 ? 1 : 0;
  const int ksb = ks - br * 36;
  const int tap = ksb >> 2, chunk = ksb & 3;
  const float* w = br ? w1 : w0;
  const int t = threadIdx.x;
  for (int i = t; i < 2688; i += 256) {
    int oc = i >> 5, kc = i & 31;
    ws[oc][kc] = w[oc * 1152 + (chunk * 32 + kc) * 9 + tap];
  }
  __syncthreads();
  const int kc = t & 31, ng = t >> 5;   // ng 0..7
  const int n0 = nh * 48 + ng * 6;
  float accv[6] = {0.f, 0.f, 0.f, 0.f, 0.f, 0.f};
#pragma unroll 4
  for (int oc = 0; oc < 84; oc++) {
    float wv_ = ws[oc][kc];
#pragma unroll
    for (int i = 0; i < 6; i++) {
      int n = n0 + i;
      float f = (n < 84) ? wf[n * 168 + br * 84 + oc] : 0.f;
      accv[i] += f * wv_;
    }
  }
#pragma unroll
  for (int i = 0; i < 6; i++) {
    int n = n0 + i;
    int nt = n >> 4, lrow = n & 15, lg = kc >> 3, j = kc & 7;
    int idx = ((ks * 6 + nt) * 64 + lg * 16 + lrow) * 8 + j;
    weffg[idx] = f2bf(n < 84 ? accv[i] : 0.f);
  }
}

// ---- kernel 3: LDS-resident row-window deform-sample + GEMM, 16 waves -------
// 512 blocks = (b:8 -> XCD) x (h:64), 1024 threads (16 waves = 4/SIMD).
// Wave wv: pxh = wv>>2 (16-px quarter), sub = wv&3 -> br = sub>>1, cp = sub&1.
// Wave: 16 px x 96 out x K=576 (9 taps x 2 chunks of 32 ch).
// r12 vs r11: pin register budget with amdgpu_waves_per_eu(4,4) -> cap 128.
// (r11 lesson: __launch_bounds__(1024,1) made the compiler target 8 waves/SIMD
// -> 64-VGPR cap -> scratch spill, WRITE_SIZE 10.75->24.5 MB, dur +5.5us.
// LDS 146KB allows only 1 block/CU = 4 waves/SIMD, so 128 is the right cap.)
__global__ __attribute__((amdgpu_flat_work_group_size(1024, 1024),
                          amdgpu_waves_per_eu(4, 4))) void deform_main(
    const u16* __restrict__ xT, const u16* __restrict__ weffg,
    const float* __restrict__ dm0, const float* __restrict__ dm1,
    const float* __restrict__ bias, float* __restrict__ out) {
  __shared__ uint4 ldsbuf[9360];   // 9 rows * 16 slots * 65 * 16B = 146.25 KiB

  const int t = threadIdx.x;
  const int wv = t >> 6, lane = t & 63;
  const int pxh = wv >> 2;             // 0..3
  const int sub = wv & 3;              // br*2 + cp
  const int br = sub >> 1, cp = sub & 1;
  const int lrow = lane & 15, lg = lane >> 4;
  const int blk = blockIdx.x;
  const int b = blk & 7, h = blk >> 3;
  const int px0 = pxh * 16;

  const u16* xb = xT + (size_t)b * 524288;

  // ---- stage rows [h-4, h+4] into LDS (coalesced 16B, 9 iters/thread) ----
#pragma unroll
  for (int k = 0; k < 9; k++) {
    int u = t + (k << 10);         // < 9216
    int i = u >> 10;               // window row 0..8
    int ul = u & 1023;             // x*16 + slot
    int ysr = min(63, max(0, h - 4 + i));
    uint4 v = *(const uint4*)(xb + ysr * 8192 + ul * 8);
    int s = ul & 15, xx = ul >> 4;
    ldsbuf[(i * 16 + s) * 65 + xx] = v;
  }
  __syncthreads();

  const float* dmb = (br ? dm1 : dm0) + (size_t)b * 73728 + h * 64 + px0 + lrow;
  const u16* wbase = weffg + (size_t)(br * 36 + cp * 2) * 3072 + lane * 8;

  f32x4 acc[6];
#pragma unroll
  for (int i = 0; i < 6; i++) acc[i] = f32x4{0.f, 0.f, 0.f, 0.f};

  float w00, w01, w10, w11;
  int x0A, x1A, yw0A, yw1A;            // yw*: window-relative rows (may be OOW)
  float dyN, dxN;
  uint4 q[8];                          // 2 chunks x 4 corners in flight

  auto tapstate = [&](int ty, int tx, float dy, float dx) {
    float pyf = (float)(h + ty - 1) + dy;
    float pxf = (float)(px0 + lrow + tx - 1) + dx;
    float y0f = floorf(pyf), x0f = floorf(pxf);
    int y0 = (int)y0f, x0 = (int)x0f;
    float wy1 = pyf - y0f, wx1 = pxf - x0f;
    float wy0 = 1.f - wy1, wx0 = 1.f - wx1;
    int y1 = y0 + 1, x1 = x0 + 1;
    wy0 *= ((u32)y0 < 64u) ? 1.f : 0.f;
    wy1 *= ((u32)y1 < 64u) ? 1.f : 0.f;
    wx0 *= ((u32)x0 < 64u) ? 1.f : 0.f;
    wx1 *= ((u32)x1 < 64u) ? 1.f : 0.f;
    w00 = wy0 * wx0; w01 = wy0 * wx1;
    w10 = wy1 * wx0; w11 = wy1 * wx1;
    int y0c = min(63, max(0, y0)), y1c = min(63, max(0, y1));
    x0A = min(63, max(0, x0));
    x1A = min(63, max(0, x1));
    yw0A = y0c - h + 4;                // in-window iff 0..8
    yw1A = y1c - h + 4;
  };

  auto issue_lds = [&]() {
    int y0w = min(8, max(0, yw0A));
    int y1w = min(8, max(0, yw1A));
#pragma unroll
    for (int c = 0; c < 2; c++) {
      int slot = cp * 8 + c * 4 + lg;
      int b0 = (y0w * 16 + slot) * 65;
      int b1 = (y1w * 16 + slot) * 65;
      q[c * 4 + 0] = ldsbuf[b0 + x0A];
      q[c * 4 + 1] = ldsbuf[b0 + x1A];
      q[c * 4 + 2] = ldsbuf[b1 + x0A];
      q[c * 4 + 3] = ldsbuf[b1 + x1A];
    }
  };

  // rare out-of-window fallback: predicated global corner loads
  auto oow_fix = [&]() {
    bool bad = ((u32)yw0A > 8u) | ((u32)yw1A > 8u);
    if (__any(bad)) {
      if ((u32)yw0A > 8u) {
        const u16* p = xb + (yw0A + h - 4) * 8192 + cp * 64 + lg * 8;
#pragma unroll
        for (int c = 0; c < 2; c++) {
          q[c * 4 + 0] = *(const uint4*)(p + c * 32 + x0A * 128);
          q[c * 4 + 1] = *(const uint4*)(p + c * 32 + x1A * 128);
        }
      }
      if ((u32)yw1A > 8u) {
        const u16* p = xb + (yw1A + h - 4) * 8192 + cp * 64 + lg * 8;
#pragma unroll
        for (int c = 0; c < 2; c++) {
          q[c * 4 + 2] = *(const uint4*)(p + c * 32 + x0A * 128);
          q[c * 4 + 3] = *(const uint4*)(p + c * 32 + x1A * 128);
        }
      }
    }
  };

  // ---- prologue: tap 0 state + reads, dm(tap1) ----
  {
    float dy0 = dmb[0], dx0 = dmb[4096];
    tapstate(0, 0, dy0, dx0);
  }
  issue_lds();
  oow_fix();
  dyN = dmb[2 * 4096];
  dxN = dmb[3 * 4096];

#pragma unroll 1
  for (int tap = 0; tap < 9; tap++) {
    const u16* wp = wbase + (size_t)(tap * 4) * 3072;

    // ---- chunk c=0 ----
    {
      uint4 wq0 = *(const uint4*)(wp);
      uint4 wq1 = *(const uint4*)(wp + 512);
      uint4 wq2 = *(const uint4*)(wp + 1024);
      uint4 wq3 = *(const uint4*)(wp + 1536);
      uint4 wq4 = *(const uint4*)(wp + 2048);
      uint4 wq5 = *(const uint4*)(wp + 2560);
      uint4 a0 = blend4(q[0], q[1], q[2], q[3], w00, w01, w10, w11);
      bf16x8 af0 = as_bf(a0);
      __builtin_amdgcn_s_setprio(1);
      acc[0] = __builtin_amdgcn_mfma_f32_16x16x32_bf16(as_bf(wq0), af0, acc[0], 0, 0, 0);
      acc[1] = __builtin_amdgcn_mfma_f32_16x16x32_bf16(as_bf(wq1), af0, acc[1], 0, 0, 0);
      acc[2] = __builtin_amdgcn_mfma_f32_16x16x32_bf16(as_bf(wq2), af0, acc[2], 0, 0, 0);
      acc[3] = __builtin_amdgcn_mfma_f32_16x16x32_bf16(as_bf(wq3), af0, acc[3], 0, 0, 0);
      acc[4] = __builtin_amdgcn_mfma_f32_16x16x32_bf16(as_bf(wq4), af0, acc[4], 0, 0, 0);
      acc[5] = __builtin_amdgcn_mfma_f32_16x16x32_bf16(as_bf(wq5), af0, acc[5], 0, 0, 0);
      __builtin_amdgcn_s_setprio(0);
    }

    // ---- chunk c=1 ----
    {
      uint4 wq0 = *(const uint4*)(wp + 3072);
      uint4 wq1 = *(const uint4*)(wp + 3584);
      uint4 wq2 = *(const uint4*)(wp + 4096);
      uint4 wq3 = *(const uint4*)(wp + 4608);
      uint4 wq4 = *(const uint4*)(wp + 5120);
      uint4 wq5 = *(const uint4*)(wp + 5632);
      uint4 a1 = blend4(q[4], q[5], q[6], q[7], w00, w01, w10, w11);

      // next tap: state + ds-issue (q now dead), dm prefetch a tap ahead
      if (tap < 8) {
        int tn = tap + 1;
        int ty = (tn * 11) >> 5;     // tn/3
        int tx = tn - ty * 3;
        tapstate(ty, tx, dyN, dxN);
        issue_lds();
        oow_fix();
        if (tap < 7) {
          dyN = dmb[(2 * tn + 2) * 4096];
          dxN = dmb[(2 * tn + 3) * 4096];
        }
      }

      bf16x8 af1 = as_bf(a1);
      __builtin_amdgcn_s_setprio(1);
      acc[0] = __builtin_amdgcn_mfma_f32_16x16x32_bf16(as_bf(wq0), af1, acc[0], 0, 0, 0);
      acc[1] = __builtin_amdgcn_mfma_f32_16x16x32_bf16(as_bf(wq1), af1, acc[1], 0, 0, 0);
      acc[2] = __builtin_amdgcn_mfma_f32_16x16x32_bf16(as_bf(wq2), af1, acc[2], 0, 0, 0);
      acc[3] = __builtin_amdgcn_mfma_f32_16x16x32_bf16(as_bf(wq3), af1, acc[3], 0, 0, 0);
      acc[4] = __builtin_amdgcn_mfma_f32_16x16x32_bf16(as_bf(wq4), af1, acc[4], 0, 0, 0);
      acc[5] = __builtin_amdgcn_mfma_f32_16x16x32_bf16(as_bf(wq5), af1, acc[5], 0, 0, 0);
      __builtin_amdgcn_s_setprio(0);
    }
  }

  // ---- reduce the 4 K-partials per pxh group (reuse staging LDS), store ----
  __syncthreads();                       // all LDS gather reads done
  const int rbase = pxh * 1152;          // uint4 units; 4*1152 = 4608 <= 9360
  if (sub > 0) {
#pragma unroll
    for (int nt = 0; nt < 6; nt++) {
      uint4 v;
      __builtin_memcpy(&v, &acc[nt], 16);
      ldsbuf[rbase + ((sub - 1) * 6 + nt) * 64 + lane] = v;
    }
  }
  __syncthreads();
  if (sub == 0) {
#pragma unroll
    for (int nt = 0; nt < 6; nt++) {
#pragma unroll
      for (int r = 0; r < 3; r++) {
        uint4 v = ldsbuf[rbase + (r * 6 + nt) * 64 + lane];
        f32x4 fv;
        __builtin_memcpy(&fv, &v, 16);
#pragma unroll
        for (int j = 0; j < 4; j++) acc[nt][j] += fv[j];
      }
    }
    float* op = out + ((size_t)b * 84 * 64 + h) * 64 + px0;
#pragma unroll
    for (int nt = 0; nt < 6; nt++) {
#pragma unroll
      for (int j = 0; j < 4; j++) {
        int o = nt * 16 + lg * 4 + j;
        if (o < 84) op[(size_t)o * 4096 + lrow] = acc[nt][j] + bias[o];
      }
    }
  }
}

// ---- launch -----------------------------------------------------------------
extern "C" void kernel_launch(void* const* d_in, const int* in_sizes, int n_in,
                              void* d_out, int out_size, void* d_ws, size_t ws_size,
                              hipStream_t stream) {
  const float* x   = (const float*)d_in[0];
  const float* dm0 = (const float*)d_in[1];
  const float* dm1 = (const float*)d_in[2];
  const float* w0  = (const float*)d_in[3];
  const float* w1  = (const float*)d_in[4];
  const float* wf  = (const float*)d_in[5];
  const float* bf  = (const float*)d_in[6];
  float* out = (float*)d_out;

  u16* xT = (u16*)d_ws;                                               // 8 MiB
  u16* weffg = (u16*)((char*)d_ws + (size_t)8 * 64 * 64 * 128 * 2);   // 432 KiB

  transpose_k<<<512, 256, 0, stream>>>(x, xT);
  weff_k<<<144, 256, 0, stream>>>(w0, w1, wf, weffg);
  deform_main<<<512, 1024, 0, stream>>>(xT, weffg, dm0, dm1, bf, out);
}